// Round 7
// baseline (459.187 us; speedup 1.0000x reference)
//
#include <hip/hip_runtime.h>
#include <hip/hip_bf16.h>

// ---------------------------------------------------------------------------
// GCN 2-layer forward on MI355X.
// Round 7: fix gemm_kernel's 32-way LDS bank conflicts (6.0M counted in R6).
//   xt stride XS was ROWS+4 (4-aligned) -> staging-store banks collapse to 2
//   (32-way, ~11x). XS = ROWS+1 (odd) spreads stores over 16 banks (4-way,
//   ~1.6x). xv inner-loop read becomes 4 scalar b32 (wave-broadcast, free)
//   since odd XS breaks b128 alignment. Everything else unchanged from R6.
// ---------------------------------------------------------------------------

#define NPP_SHIFT 9
#define NPP 512
#define MAXP 256
#define NB 512  // scatter blocks in passes A/C

// ---- Pass A: per-block histograms of src-partition and dst-partition ----
__launch_bounds__(256)
__global__ void passA_count(const int* __restrict__ src, const int* __restrict__ dst,
                            int E, int P, int* __restrict__ counts_src,
                            int* __restrict__ counts_dst) {
    __shared__ int h1[MAXP], h2[MAXP];
    int tid = threadIdx.x;
    for (int i = tid; i < P; i += 256) { h1[i] = 0; h2[i] = 0; }
    __syncthreads();
    int per_block = (E + NB - 1) / NB;
    int e0 = blockIdx.x * per_block;
    int e1 = min(e0 + per_block, E);
    for (int e = e0 + tid; e < e1; e += 256) {
        atomicAdd(&h1[src[e] >> NPP_SHIFT], 1);
        atomicAdd(&h2[dst[e] >> NPP_SHIFT], 1);
    }
    __syncthreads();
    for (int i = tid; i < P; i += 256) {
        counts_src[(size_t)blockIdx.x * P + i] = h1[i];
        counts_dst[(size_t)blockIdx.x * P + i] = h2[i];
    }
}

// ---- Pass B: exclusive scan across blocks for each (stream, partition) --
__launch_bounds__(1024)
__global__ void scanB(const int* __restrict__ counts, int* __restrict__ offs,
                      int* __restrict__ ptot, int P) {
    __shared__ int s[1024];
    int tid = threadIdx.x;
    int p = blockIdx.x % P;
    int st = blockIdx.x / P;
    const int* c = counts + (size_t)st * NB * P;
    int v = (tid < NB) ? c[(size_t)tid * P + p] : 0;
    s[tid] = v;
    __syncthreads();
    for (int off = 1; off < 1024; off <<= 1) {
        int t = (tid >= off) ? s[tid - off] : 0;
        __syncthreads();
        s[tid] += t;
        __syncthreads();
    }
    if (tid < NB) offs[(size_t)st * NB * P + (size_t)tid * P + p] = s[tid] - v;
    if (tid == 1023) ptot[st * P + p] = s[1023];
}

// ---- Pass B2: exclusive scan over partitions, per stream (P <= 256) -----
__launch_bounds__(512)
__global__ void scanP(const int* __restrict__ ptot, int* __restrict__ pbase, int P) {
    __shared__ int s[512];
    int tid = threadIdx.x;
    int seg = tid >> 8;
    int idx = tid & 255;
    int v = (idx < P) ? ptot[seg * P + idx] : 0;
    s[tid] = v;
    __syncthreads();
    for (int off = 1; off < 256; off <<= 1) {
        int t = (idx >= off) ? s[tid - off] : 0;
        __syncthreads();
        s[tid] += t;
        __syncthreads();
    }
    if (idx < P) pbase[seg * P + idx] = s[tid] - v;
}

// ---- Pass C: scatter into partition-bucketed buffers (LDS cursors) ------
__launch_bounds__(256)
__global__ void passC_scatter(const int* __restrict__ src, const int* __restrict__ dst,
                              int E, int P, const int* __restrict__ offs,
                              const int* __restrict__ pbase,
                              int* __restrict__ ebuf_src, int2* __restrict__ ebuf_dst) {
    __shared__ int cur1[MAXP], cur2[MAXP];
    int tid = threadIdx.x;
    for (int i = tid; i < P; i += 256) {
        cur1[i] = pbase[i] + offs[(size_t)blockIdx.x * P + i];
        cur2[i] = pbase[P + i] + offs[(size_t)NB * P + (size_t)blockIdx.x * P + i];
    }
    __syncthreads();
    int per_block = (E + NB - 1) / NB;
    int e0 = blockIdx.x * per_block;
    int e1 = min(e0 + per_block, E);
    for (int e = e0 + tid; e < e1; e += 256) {
        int s = src[e];
        int d = dst[e];
        int pos1 = atomicAdd(&cur1[s >> NPP_SHIFT], 1);
        ebuf_src[pos1] = s;
        int pos2 = atomicAdd(&cur2[d >> NPP_SHIFT], 1);
        ebuf_dst[pos2] = make_int2(d, s);
    }
}

// ---- Pass D: per-partition degree/norm/row_start/csr build --------------
__launch_bounds__(512)
__global__ void passD_build(const int* __restrict__ ebuf_src, const int2* __restrict__ ebuf_dst,
                            const int* __restrict__ ptot, const int* __restrict__ pbase,
                            float* __restrict__ norm_src, int* __restrict__ row_start,
                            int* __restrict__ csr_src, int N, int E, int P) {
    __shared__ int hs[NPP], hd[NPP], sc[NPP];
    int tid = threadIdx.x;
    int p = blockIdx.x;
    int node_lo = p << NPP_SHIFT;
    int nl = min(NPP, N - node_lo);
    hs[tid] = 0;
    hd[tid] = 0;
    __syncthreads();
    int nsrc = ptot[p];
    int base_s = pbase[p];
    for (int i = tid; i < nsrc; i += 512)
        atomicAdd(&hs[ebuf_src[base_s + i] - node_lo], 1);
    int ndst = ptot[P + p];
    int base_d = pbase[P + p];
    for (int i = tid; i < ndst; i += 512)
        atomicAdd(&hd[ebuf_dst[base_d + i].x - node_lo], 1);
    __syncthreads();
    if (tid < nl) norm_src[node_lo + tid] = rsqrtf((float)max(hs[tid], 1));
    int myh = hd[tid];
    sc[tid] = myh;
    __syncthreads();
    for (int off = 1; off < 512; off <<= 1) {
        int t = (tid >= off) ? sc[tid - off] : 0;
        __syncthreads();
        sc[tid] += t;
        __syncthreads();
    }
    int row0 = base_d + sc[tid] - myh;
    if (tid < nl) row_start[node_lo + tid] = row0;
    if (p == P - 1 && tid == 0) row_start[N] = E;
    __syncthreads();
    hd[tid] = row0;  // reuse as cursor
    __syncthreads();
    for (int i = tid; i < ndst; i += 512) {
        int2 r = ebuf_dst[base_d + i];
        int pos = atomicAdd(&hd[r.x - node_lo], 1);
        csr_src[pos] = r.y;
    }
}

// graph_ids is sorted: g_start[g] = lower_bound(gids, g). One tiny block.
__global__ void gstart_kernel(const int* __restrict__ gids, int* __restrict__ g_start,
                              int n, int G) {
    int g = threadIdx.x;
    if (g > G) return;
    int lo = 0, hi = n;
    while (lo < hi) {
        int mid = (lo + hi) >> 1;
        if (gids[mid] < g) lo = mid + 1; else hi = mid;
    }
    g_start[g] = lo;
}

// ---- Dense GEMM: out[n x COLS] = (x * norm)[n x 128] @ w[128 x COLS] ----
// XS = ROWS+1 (odd): staging stores spread over 16 banks (4-way), xv reads
// are scalar wave-broadcasts (conflict-free).
template <int COLS>
__launch_bounds__(256)
__global__ void gemm_kernel(const float* __restrict__ x, const float* __restrict__ w,
                            const float* __restrict__ norm, __hip_bfloat16* __restrict__ out,
                            int n) {
    constexpr int K = 128;
    constexpr int KT = 64;
    constexpr int CG = COLS / 4;
    constexpr int RG = 256 / CG;
    constexpr int ROWS = RG * 4;
    constexpr int XS = ROWS + 1;   // odd stride: breaks the {bank, bank+16} collapse
    __shared__ float wlds[KT * COLS];
    __shared__ float xt[K * XS];

    const int tid = threadIdx.x;
    const int cg = tid % CG;
    const int rg = tid / CG;
    const int ntiles = (n + ROWS - 1) / ROWS;

    for (int tile = blockIdx.x; tile < ntiles; tile += gridDim.x) {
        const int row0 = tile * ROWS;
        __syncthreads();
        for (int i = tid; i < (K / 4) * ROWS; i += 256) {
            int r = i / (K / 4);
            int k4 = (i % (K / 4)) * 4;
            int gr = row0 + r;
            float4 v = {0.f, 0.f, 0.f, 0.f};
            float nm = 0.f;
            if (gr < n) {
                v = reinterpret_cast<const float4*>(x + (size_t)gr * K)[k4 >> 2];
                nm = norm[gr];
            }
            xt[(k4 + 0) * XS + r] = v.x * nm;
            xt[(k4 + 1) * XS + r] = v.y * nm;
            xt[(k4 + 2) * XS + r] = v.z * nm;
            xt[(k4 + 3) * XS + r] = v.w * nm;
        }
        float acc[4][4] = {};
        for (int kt = 0; kt < K; kt += KT) {
            __syncthreads();
            for (int i = tid; i < KT * COLS / 4; i += 256) {
                reinterpret_cast<float4*>(wlds)[i] =
                    reinterpret_cast<const float4*>(w + (size_t)kt * COLS)[i];
            }
            __syncthreads();
#pragma unroll 4
            for (int k = 0; k < KT; ++k) {
                float4 wv = *reinterpret_cast<const float4*>(&wlds[k * COLS + cg * 4]);
                const float* xrow = &xt[(kt + k) * XS + rg * 4];
                float x0 = xrow[0], x1 = xrow[1], x2v = xrow[2], x3 = xrow[3];
                acc[0][0] = fmaf(x0, wv.x, acc[0][0]);
                acc[0][1] = fmaf(x0, wv.y, acc[0][1]);
                acc[0][2] = fmaf(x0, wv.z, acc[0][2]);
                acc[0][3] = fmaf(x0, wv.w, acc[0][3]);
                acc[1][0] = fmaf(x1, wv.x, acc[1][0]);
                acc[1][1] = fmaf(x1, wv.y, acc[1][1]);
                acc[1][2] = fmaf(x1, wv.z, acc[1][2]);
                acc[1][3] = fmaf(x1, wv.w, acc[1][3]);
                acc[2][0] = fmaf(x2v, wv.x, acc[2][0]);
                acc[2][1] = fmaf(x2v, wv.y, acc[2][1]);
                acc[2][2] = fmaf(x2v, wv.z, acc[2][2]);
                acc[2][3] = fmaf(x2v, wv.w, acc[2][3]);
                acc[3][0] = fmaf(x3, wv.x, acc[3][0]);
                acc[3][1] = fmaf(x3, wv.y, acc[3][1]);
                acc[3][2] = fmaf(x3, wv.z, acc[3][2]);
                acc[3][3] = fmaf(x3, wv.w, acc[3][3]);
            }
        }
        for (int r = 0; r < 4; ++r) {
            int gr = row0 + rg * 4 + r;
            if (gr < n) {
                union { ushort4 u4; __hip_bfloat16 h[4]; } pk;
                pk.h[0] = __float2bfloat16(acc[r][0]);
                pk.h[1] = __float2bfloat16(acc[r][1]);
                pk.h[2] = __float2bfloat16(acc[r][2]);
                pk.h[3] = __float2bfloat16(acc[r][3]);
                reinterpret_cast<ushort4*>(out + (size_t)gr * COLS)[cg] = pk.u4;
            }
        }
    }
}

// ---- SpMM layer 1: wave per dst node, 128 bf16 feats = uint(bf16x2)/lane --
__launch_bounds__(256)
__global__ void spmm1_kernel(const __hip_bfloat16* __restrict__ h,
                             const int* __restrict__ row_start,
                             const int* __restrict__ csr_src,
                             const float* __restrict__ b1, float* __restrict__ out, int n) {
    int gw = (blockIdx.x * blockDim.x + threadIdx.x) >> 6;
    int lane = threadIdx.x & 63;
    if (gw >= n) return;
    int e0 = row_start[gw];
    int e1 = row_start[gw + 1];
    const uint* hp = reinterpret_cast<const uint*>(h);
    float2 acc = {0.f, 0.f};
    int e = e0;
    for (; e + 1 < e1; e += 2) {
        int s0 = csr_src[e];
        int s1 = csr_src[e + 1];
        uint v0 = hp[(size_t)s0 * 64 + lane];
        uint v1 = hp[(size_t)s1 * 64 + lane];
        acc.x += __uint_as_float(v0 << 16);
        acc.y += __uint_as_float(v0 & 0xffff0000u);
        acc.x += __uint_as_float(v1 << 16);
        acc.y += __uint_as_float(v1 & 0xffff0000u);
    }
    if (e < e1) {
        uint v0 = hp[(size_t)csr_src[e] * 64 + lane];
        acc.x += __uint_as_float(v0 << 16);
        acc.y += __uint_as_float(v0 & 0xffff0000u);
    }
    float nd = rsqrtf((float)max(e1 - e0, 1));
    float2 bb = reinterpret_cast<const float2*>(b1)[lane];
    float2 o;
    o.x = fmaxf(fmaf(acc.x, nd, bb.x), 0.f);
    o.y = fmaxf(fmaf(acc.y, nd, bb.y), 0.f);
    reinterpret_cast<float2*>(out + (size_t)gw * 128)[lane] = o;
}

// ---- SpMM layer 2: wave per dst node, 64 bf16 feats = ushort/lane --------
__launch_bounds__(256)
__global__ void spmm2_kernel(const __hip_bfloat16* __restrict__ h,
                             const int* __restrict__ row_start,
                             const int* __restrict__ csr_src,
                             const float* __restrict__ b2, float* __restrict__ y, int n) {
    int gw = (blockIdx.x * blockDim.x + threadIdx.x) >> 6;
    int lane = threadIdx.x & 63;
    if (gw >= n) return;
    int e0 = row_start[gw];
    int e1 = row_start[gw + 1];
    const ushort* hp = reinterpret_cast<const ushort*>(h);
    float acc = 0.f;
    int e = e0;
    for (; e + 1 < e1; e += 2) {
        int s0 = csr_src[e];
        int s1 = csr_src[e + 1];
        uint v0 = hp[(size_t)s0 * 64 + lane];
        uint v1 = hp[(size_t)s1 * 64 + lane];
        acc += __uint_as_float(v0 << 16);
        acc += __uint_as_float(v1 << 16);
    }
    if (e < e1) {
        uint v0 = hp[(size_t)csr_src[e] * 64 + lane];
        acc += __uint_as_float(v0 << 16);
    }
    float nd = rsqrtf((float)max(e1 - e0, 1));
    y[(size_t)gw * 64 + lane] = fmaxf(fmaf(acc, nd, b2[lane]), 0.f);
}

// ---- Segmented per-graph pooling over sorted node ranges ----------------
#define POOL_CHUNKS 8
__launch_bounds__(256)
__global__ void pool_kernel(const float* __restrict__ y, const int* __restrict__ g_start,
                            float* __restrict__ gsum) {
    int g = blockIdx.x / POOL_CHUNKS;
    int c = blockIdx.x % POOL_CHUNKS;
    int s = g_start[g];
    int e = g_start[g + 1];
    int lane = threadIdx.x & 63;
    int wave = threadIdx.x >> 6;
    float acc = 0.f;
    for (int i = s + c * 4 + wave; i < e; i += POOL_CHUNKS * 4) {
        acc += y[(size_t)i * 64 + lane];
    }
    __shared__ float sbuf[4][64];
    sbuf[wave][lane] = acc;
    __syncthreads();
    if (wave == 0) {
        float v = sbuf[0][lane] + sbuf[1][lane] + sbuf[2][lane] + sbuf[3][lane];
        atomicAdd(&gsum[(size_t)g * 64 + lane], v);
    }
}

__global__ void finalize_kernel(const float* __restrict__ gsum, const int* __restrict__ g_start,
                                float* __restrict__ out, int total) {
    int i = blockIdx.x * blockDim.x + threadIdx.x;
    if (i < total) {
        int g = i >> 6;
        float cnt = (float)(g_start[g + 1] - g_start[g]);
        out[i] = gsum[i] / fmaxf(cnt, 1.f);
    }
}

extern "C" void kernel_launch(void* const* d_in, const int* in_sizes, int n_in,
                              void* d_out, int out_size, void* d_ws, size_t ws_size,
                              hipStream_t stream) {
    const float* features = (const float*)d_in[0];
    const float* W1 = (const float*)d_in[1];
    const float* b1 = (const float*)d_in[2];
    const float* W2 = (const float*)d_in[3];
    const float* b2 = (const float*)d_in[4];
    const int* src = (const int*)d_in[5];
    const int* dst = (const int*)d_in[6];
    const int* gids = (const int*)d_in[7];
    const int N = in_sizes[7];
    const int E = in_sizes[5];
    const int G = out_size / 64;
    float* out = (float*)d_out;
    const int P = (N + NPP - 1) >> NPP_SHIFT;

    // --- bump allocator over d_ws (256 B aligned) ---
    char* ws = (char*)d_ws;
    size_t off = 0;
    auto alloc = [&](size_t bytes) -> void* {
        void* p = ws + off;
        off = (off + bytes + 255) & ~(size_t)255;
        return p;
    };
    int* counts = (int*)alloc((size_t)2 * NB * P * 4);
    int* offs = (int*)alloc((size_t)2 * NB * P * 4);
    int* ptot = (int*)alloc((size_t)2 * P * 4);
    int* pbase = (int*)alloc((size_t)2 * P * 4);
    int* ebuf_src = (int*)alloc((size_t)E * 4);
    int2* ebuf_dst = (int2*)alloc((size_t)E * 8);
    float* norm_src = (float*)alloc((size_t)N * 4);
    int* row_start = (int*)alloc((size_t)(N + 1) * 4);
    int* csr_src = (int*)alloc((size_t)E * 4);
    int* g_start = (int*)alloc((size_t)(G + 1) * 4);
    float* gsum = (float*)alloc((size_t)G * 64 * 4);
    __hip_bfloat16* h1 = (__hip_bfloat16*)alloc((size_t)N * 128 * 2);  // reused as h2
    float* x2 = (float*)alloc((size_t)N * 128 * 4);                    // reused as y
    __hip_bfloat16* h2 = h1;
    float* y = x2;

    hipMemsetAsync(gsum, 0, (size_t)G * 64 * 4, stream);

    const int B = 256;
    // --- atomic-free graph build ---
    passA_count<<<NB, 256, 0, stream>>>(src, dst, E, P, counts, counts + (size_t)NB * P);
    scanB<<<2 * P, 1024, 0, stream>>>(counts, offs, ptot, P);
    scanP<<<1, 512, 0, stream>>>(ptot, pbase, P);
    passC_scatter<<<NB, 256, 0, stream>>>(src, dst, E, P, offs, pbase, ebuf_src, ebuf_dst);
    passD_build<<<P, 512, 0, stream>>>(ebuf_src, ebuf_dst, ptot, pbase, norm_src, row_start,
                                       csr_src, N, E, P);
    gstart_kernel<<<1, 256, 0, stream>>>(gids, g_start, N, G);

    // Layer 1
    gemm_kernel<128><<<768, 256, 0, stream>>>(features, W1, norm_src, h1, N);
    spmm1_kernel<<<(N * 64 + B - 1) / B, B, 0, stream>>>(h1, row_start, csr_src, b1, x2, N);
    // Layer 2
    gemm_kernel<64><<<768, 256, 0, stream>>>(x2, W2, norm_src, h2, N);
    spmm2_kernel<<<(N * 64 + B - 1) / B, B, 0, stream>>>(h2, row_start, csr_src, b2, y, N);
    // Per-graph mean (sorted gids -> contiguous ranges)
    pool_kernel<<<G * POOL_CHUNKS, 256, 0, stream>>>(y, g_start, gsum);
    finalize_kernel<<<(out_size + B - 1) / B, B, 0, stream>>>(gsum, g_start, out, out_size);
}

// Round 8
// 406.242 us; speedup vs baseline: 1.1303x; 1.1303x over previous
//
#include <hip/hip_runtime.h>
#include <hip/hip_bf16.h>

// ---------------------------------------------------------------------------
// GCN 2-layer forward on MI355X.
// Round 8: bf16 MFMA GEMMs (16x16x32) replace the fp32 vector GEMMs.
//   R7 post-mortem: 6M LDS-conflict cycles = ~10 us device-wide (hidden);
//   the vector GEMMs were FMA/LDS-issue bound (~150-200 us combined).
//   MFMA design: wave per 16-row tile, W pre-permuted in LDS to B-frag
//   order (one ds_read_b128 per frag), A-frags from global, no barriers
//   in the K loop. spmm1 now writes x2*norm_src as packed bf16 (halves
//   the write + lets gemm2 consume bf16 directly).
// ---------------------------------------------------------------------------

#define NPP_SHIFT 9
#define NPP 512
#define MAXP 256
#define NB 512

typedef __attribute__((ext_vector_type(8))) short frag8;
typedef __attribute__((ext_vector_type(4))) float f32x4;

// ---- Pass A: per-block histograms of src-partition and dst-partition ----
__launch_bounds__(256)
__global__ void passA_count(const int* __restrict__ src, const int* __restrict__ dst,
                            int E, int P, int* __restrict__ counts_src,
                            int* __restrict__ counts_dst) {
    __shared__ int h1[MAXP], h2[MAXP];
    int tid = threadIdx.x;
    for (int i = tid; i < P; i += 256) { h1[i] = 0; h2[i] = 0; }
    __syncthreads();
    int per_block = (E + NB - 1) / NB;
    int e0 = blockIdx.x * per_block;
    int e1 = min(e0 + per_block, E);
    for (int e = e0 + tid; e < e1; e += 256) {
        atomicAdd(&h1[src[e] >> NPP_SHIFT], 1);
        atomicAdd(&h2[dst[e] >> NPP_SHIFT], 1);
    }
    __syncthreads();
    for (int i = tid; i < P; i += 256) {
        counts_src[(size_t)blockIdx.x * P + i] = h1[i];
        counts_dst[(size_t)blockIdx.x * P + i] = h2[i];
    }
}

__launch_bounds__(1024)
__global__ void scanB(const int* __restrict__ counts, int* __restrict__ offs,
                      int* __restrict__ ptot, int P) {
    __shared__ int s[1024];
    int tid = threadIdx.x;
    int p = blockIdx.x % P;
    int st = blockIdx.x / P;
    const int* c = counts + (size_t)st * NB * P;
    int v = (tid < NB) ? c[(size_t)tid * P + p] : 0;
    s[tid] = v;
    __syncthreads();
    for (int off = 1; off < 1024; off <<= 1) {
        int t = (tid >= off) ? s[tid - off] : 0;
        __syncthreads();
        s[tid] += t;
        __syncthreads();
    }
    if (tid < NB) offs[(size_t)st * NB * P + (size_t)tid * P + p] = s[tid] - v;
    if (tid == 1023) ptot[st * P + p] = s[1023];
}

__launch_bounds__(512)
__global__ void scanP(const int* __restrict__ ptot, int* __restrict__ pbase, int P) {
    __shared__ int s[512];
    int tid = threadIdx.x;
    int seg = tid >> 8;
    int idx = tid & 255;
    int v = (idx < P) ? ptot[seg * P + idx] : 0;
    s[tid] = v;
    __syncthreads();
    for (int off = 1; off < 256; off <<= 1) {
        int t = (idx >= off) ? s[tid - off] : 0;
        __syncthreads();
        s[tid] += t;
        __syncthreads();
    }
    if (idx < P) pbase[seg * P + idx] = s[tid] - v;
}

__launch_bounds__(256)
__global__ void passC_scatter(const int* __restrict__ src, const int* __restrict__ dst,
                              int E, int P, const int* __restrict__ offs,
                              const int* __restrict__ pbase,
                              int* __restrict__ ebuf_src, int2* __restrict__ ebuf_dst) {
    __shared__ int cur1[MAXP], cur2[MAXP];
    int tid = threadIdx.x;
    for (int i = tid; i < P; i += 256) {
        cur1[i] = pbase[i] + offs[(size_t)blockIdx.x * P + i];
        cur2[i] = pbase[P + i] + offs[(size_t)NB * P + (size_t)blockIdx.x * P + i];
    }
    __syncthreads();
    int per_block = (E + NB - 1) / NB;
    int e0 = blockIdx.x * per_block;
    int e1 = min(e0 + per_block, E);
    for (int e = e0 + tid; e < e1; e += 256) {
        int s = src[e];
        int d = dst[e];
        int pos1 = atomicAdd(&cur1[s >> NPP_SHIFT], 1);
        ebuf_src[pos1] = s;
        int pos2 = atomicAdd(&cur2[d >> NPP_SHIFT], 1);
        ebuf_dst[pos2] = make_int2(d, s);
    }
}

__launch_bounds__(512)
__global__ void passD_build(const int* __restrict__ ebuf_src, const int2* __restrict__ ebuf_dst,
                            const int* __restrict__ ptot, const int* __restrict__ pbase,
                            float* __restrict__ norm_src, int* __restrict__ row_start,
                            int* __restrict__ csr_src, int N, int E, int P) {
    __shared__ int hs[NPP], hd[NPP], sc[NPP];
    int tid = threadIdx.x;
    int p = blockIdx.x;
    int node_lo = p << NPP_SHIFT;
    int nl = min(NPP, N - node_lo);
    hs[tid] = 0;
    hd[tid] = 0;
    __syncthreads();
    int nsrc = ptot[p];
    int base_s = pbase[p];
    for (int i = tid; i < nsrc; i += 512)
        atomicAdd(&hs[ebuf_src[base_s + i] - node_lo], 1);
    int ndst = ptot[P + p];
    int base_d = pbase[P + p];
    for (int i = tid; i < ndst; i += 512)
        atomicAdd(&hd[ebuf_dst[base_d + i].x - node_lo], 1);
    __syncthreads();
    if (tid < nl) norm_src[node_lo + tid] = rsqrtf((float)max(hs[tid], 1));
    int myh = hd[tid];
    sc[tid] = myh;
    __syncthreads();
    for (int off = 1; off < 512; off <<= 1) {
        int t = (tid >= off) ? sc[tid - off] : 0;
        __syncthreads();
        sc[tid] += t;
        __syncthreads();
    }
    int row0 = base_d + sc[tid] - myh;
    if (tid < nl) row_start[node_lo + tid] = row0;
    if (p == P - 1 && tid == 0) row_start[N] = E;
    __syncthreads();
    hd[tid] = row0;  // reuse as cursor
    __syncthreads();
    for (int i = tid; i < ndst; i += 512) {
        int2 r = ebuf_dst[base_d + i];
        int pos = atomicAdd(&hd[r.x - node_lo], 1);
        csr_src[pos] = r.y;
    }
}

__global__ void gstart_kernel(const int* __restrict__ gids, int* __restrict__ g_start,
                              int n, int G) {
    int g = threadIdx.x;
    if (g > G) return;
    int lo = 0, hi = n;
    while (lo < hi) {
        int mid = (lo + hi) >> 1;
        if (gids[mid] < g) lo = mid + 1; else hi = mid;
    }
    g_start[g] = lo;
}

// ---- MFMA GEMM: out[n x COLS](bf16) = A[n x 128] @ W[128 x COLS] --------
// BF16IN=false: A = fp32 x * norm (gemm1).  BF16IN=true: A = bf16 (gemm2).
// W staged in LDS pre-permuted to B-fragment order:
//   frag(c,t) lane holds B[k = c*32 + (lane>>4)*8 + j][n = t*16 + (lane&15)]
//   at short index ((c*NT+t)*64 + lane)*8 + j  ->  one ds_read_b128 per frag.
template <int COLS, bool BF16IN>
__launch_bounds__(256)
__global__ void gemm_mfma(const void* __restrict__ xin, const float* __restrict__ w,
                          const float* __restrict__ norm,
                          __hip_bfloat16* __restrict__ out, int n) {
    constexpr int NT = COLS / 16;
    __shared__ short wlds[4 * NT * 64 * 8];
    const int tid = threadIdx.x;
    // stage W (fp32, row-major 128 x COLS) -> permuted bf16
    for (int i = tid; i < 128 * COLS / 4; i += 256) {
        int k = (i * 4) / COLS;
        int n0 = (i * 4) % COLS;
        float4 wv = reinterpret_cast<const float4*>(w)[i];
        int c = k >> 5, q = (k >> 3) & 3, j = k & 7;
        float vals[4] = {wv.x, wv.y, wv.z, wv.w};
#pragma unroll
        for (int u = 0; u < 4; ++u) {
            int nn = n0 + u;
            int t = nn >> 4;
            int ln = (q << 4) | (nn & 15);
            union { __hip_bfloat16 b; short s; } cv;
            cv.b = __float2bfloat16(vals[u]);
            wlds[(((c * NT + t) << 6) | ln) * 8 + j] = cv.s;
        }
    }
    __syncthreads();

    const int lane = tid & 63;
    const int wid = tid >> 6;
    const int m = lane & 15;     // A row within tile / D col within tile
    const int q = lane >> 4;     // quad
    const int ntiles = (n + 15) >> 4;
    const frag8* wfr = reinterpret_cast<const frag8*>(wlds);

    for (int wt = blockIdx.x * 4 + wid; wt < ntiles; wt += gridDim.x * 4) {
        const int row = (wt << 4) + m;
        frag8 af[4];
        if (row < n) {
            if constexpr (BF16IN) {
                const frag8* xp = reinterpret_cast<const frag8*>(
                    (const __hip_bfloat16*)xin + (size_t)row * 128);
#pragma unroll
                for (int c = 0; c < 4; ++c) af[c] = xp[c * 4 + q];
            } else {
                const float* xp = (const float*)xin + (size_t)row * 128;
                float nm = norm[row];
#pragma unroll
                for (int c = 0; c < 4; ++c) {
                    int base = c * 32 + q * 8;
                    float4 v0 = *reinterpret_cast<const float4*>(xp + base);
                    float4 v1 = *reinterpret_cast<const float4*>(xp + base + 4);
                    union { frag8 f; short s[8]; } a;
                    union { __hip_bfloat16 b; short s; } cv;
                    cv.b = __float2bfloat16(v0.x * nm); a.s[0] = cv.s;
                    cv.b = __float2bfloat16(v0.y * nm); a.s[1] = cv.s;
                    cv.b = __float2bfloat16(v0.z * nm); a.s[2] = cv.s;
                    cv.b = __float2bfloat16(v0.w * nm); a.s[3] = cv.s;
                    cv.b = __float2bfloat16(v1.x * nm); a.s[4] = cv.s;
                    cv.b = __float2bfloat16(v1.y * nm); a.s[5] = cv.s;
                    cv.b = __float2bfloat16(v1.z * nm); a.s[6] = cv.s;
                    cv.b = __float2bfloat16(v1.w * nm); a.s[7] = cv.s;
                    af[c] = a.f;
                }
            }
        } else {
#pragma unroll
            for (int c = 0; c < 4; ++c) af[c] = frag8{0, 0, 0, 0, 0, 0, 0, 0};
        }
        f32x4 acc[NT] = {};
#pragma unroll
        for (int c = 0; c < 4; ++c)
#pragma unroll
            for (int t = 0; t < NT; ++t)
                acc[t] = __builtin_amdgcn_mfma_f32_16x16x32_bf16(
                    af[c], wfr[(c * NT + t) * 64 + lane], acc[t], 0, 0, 0);
        // D: col = lane&15 (=m), row = q*4 + r
#pragma unroll
        for (int r = 0; r < 4; ++r) {
            int grow = (wt << 4) + q * 4 + r;
            if (grow < n) {
#pragma unroll
                for (int t = 0; t < NT; ++t)
                    out[(size_t)grow * COLS + t * 16 + m] = __float2bfloat16(acc[t][r]);
            }
        }
    }
}

// ---- SpMM layer 1: wave per dst node; emits x2*norm_src as packed bf16 --
__launch_bounds__(256)
__global__ void spmm1_kernel(const __hip_bfloat16* __restrict__ h,
                             const int* __restrict__ row_start,
                             const int* __restrict__ csr_src,
                             const float* __restrict__ b1,
                             const float* __restrict__ norm_src,
                             uint* __restrict__ out, int n) {
    int gw = (blockIdx.x * blockDim.x + threadIdx.x) >> 6;
    int lane = threadIdx.x & 63;
    if (gw >= n) return;
    int e0 = row_start[gw];
    int e1 = row_start[gw + 1];
    const uint* hp = reinterpret_cast<const uint*>(h);
    float2 acc = {0.f, 0.f};
    int e = e0;
    for (; e + 1 < e1; e += 2) {
        int s0 = csr_src[e];
        int s1 = csr_src[e + 1];
        uint v0 = hp[(size_t)s0 * 64 + lane];
        uint v1 = hp[(size_t)s1 * 64 + lane];
        acc.x += __uint_as_float(v0 << 16);
        acc.y += __uint_as_float(v0 & 0xffff0000u);
        acc.x += __uint_as_float(v1 << 16);
        acc.y += __uint_as_float(v1 & 0xffff0000u);
    }
    if (e < e1) {
        uint v0 = hp[(size_t)csr_src[e] * 64 + lane];
        acc.x += __uint_as_float(v0 << 16);
        acc.y += __uint_as_float(v0 & 0xffff0000u);
    }
    float nd = rsqrtf((float)max(e1 - e0, 1));
    float ns = norm_src[gw];
    float2 bb = reinterpret_cast<const float2*>(b1)[lane];
    float ox = fmaxf(fmaf(acc.x, nd, bb.x), 0.f) * ns;
    float oy = fmaxf(fmaf(acc.y, nd, bb.y), 0.f) * ns;
    union { __hip_bfloat16 b; ushort s; } cx, cy;
    cx.b = __float2bfloat16(ox);
    cy.b = __float2bfloat16(oy);
    out[(size_t)gw * 64 + lane] = (uint)cx.s | ((uint)cy.s << 16);
}

// ---- SpMM layer 2: wave per dst node, 64 bf16 feats = ushort/lane --------
__launch_bounds__(256)
__global__ void spmm2_kernel(const __hip_bfloat16* __restrict__ h,
                             const int* __restrict__ row_start,
                             const int* __restrict__ csr_src,
                             const float* __restrict__ b2, float* __restrict__ y, int n) {
    int gw = (blockIdx.x * blockDim.x + threadIdx.x) >> 6;
    int lane = threadIdx.x & 63;
    if (gw >= n) return;
    int e0 = row_start[gw];
    int e1 = row_start[gw + 1];
    const ushort* hp = reinterpret_cast<const ushort*>(h);
    float acc = 0.f;
    int e = e0;
    for (; e + 1 < e1; e += 2) {
        int s0 = csr_src[e];
        int s1 = csr_src[e + 1];
        uint v0 = hp[(size_t)s0 * 64 + lane];
        uint v1 = hp[(size_t)s1 * 64 + lane];
        acc += __uint_as_float(v0 << 16);
        acc += __uint_as_float(v1 << 16);
    }
    if (e < e1) {
        uint v0 = hp[(size_t)csr_src[e] * 64 + lane];
        acc += __uint_as_float(v0 << 16);
    }
    float nd = rsqrtf((float)max(e1 - e0, 1));
    y[(size_t)gw * 64 + lane] = fmaxf(fmaf(acc, nd, b2[lane]), 0.f);
}

// ---- Segmented per-graph pooling over sorted node ranges ----------------
#define POOL_CHUNKS 8
__launch_bounds__(256)
__global__ void pool_kernel(const float* __restrict__ y, const int* __restrict__ g_start,
                            float* __restrict__ gsum) {
    int g = blockIdx.x / POOL_CHUNKS;
    int c = blockIdx.x % POOL_CHUNKS;
    int s = g_start[g];
    int e = g_start[g + 1];
    int lane = threadIdx.x & 63;
    int wave = threadIdx.x >> 6;
    float acc = 0.f;
    for (int i = s + c * 4 + wave; i < e; i += POOL_CHUNKS * 4) {
        acc += y[(size_t)i * 64 + lane];
    }
    __shared__ float sbuf[4][64];
    sbuf[wave][lane] = acc;
    __syncthreads();
    if (wave == 0) {
        float v = sbuf[0][lane] + sbuf[1][lane] + sbuf[2][lane] + sbuf[3][lane];
        atomicAdd(&gsum[(size_t)g * 64 + lane], v);
    }
}

__global__ void finalize_kernel(const float* __restrict__ gsum, const int* __restrict__ g_start,
                                float* __restrict__ out, int total) {
    int i = blockIdx.x * blockDim.x + threadIdx.x;
    if (i < total) {
        int g = i >> 6;
        float cnt = (float)(g_start[g + 1] - g_start[g]);
        out[i] = gsum[i] / fmaxf(cnt, 1.f);
    }
}

extern "C" void kernel_launch(void* const* d_in, const int* in_sizes, int n_in,
                              void* d_out, int out_size, void* d_ws, size_t ws_size,
                              hipStream_t stream) {
    const float* features = (const float*)d_in[0];
    const float* W1 = (const float*)d_in[1];
    const float* b1 = (const float*)d_in[2];
    const float* W2 = (const float*)d_in[3];
    const float* b2 = (const float*)d_in[4];
    const int* src = (const int*)d_in[5];
    const int* dst = (const int*)d_in[6];
    const int* gids = (const int*)d_in[7];
    const int N = in_sizes[7];
    const int E = in_sizes[5];
    const int G = out_size / 64;
    float* out = (float*)d_out;
    const int P = (N + NPP - 1) >> NPP_SHIFT;

    char* ws = (char*)d_ws;
    size_t off = 0;
    auto alloc = [&](size_t bytes) -> void* {
        void* p = ws + off;
        off = (off + bytes + 255) & ~(size_t)255;
        return p;
    };
    int* counts = (int*)alloc((size_t)2 * NB * P * 4);
    int* offs = (int*)alloc((size_t)2 * NB * P * 4);
    int* ptot = (int*)alloc((size_t)2 * P * 4);
    int* pbase = (int*)alloc((size_t)2 * P * 4);
    int* ebuf_src = (int*)alloc((size_t)E * 4);
    int2* ebuf_dst = (int2*)alloc((size_t)E * 8);
    float* norm_src = (float*)alloc((size_t)N * 4);
    int* row_start = (int*)alloc((size_t)(N + 1) * 4);
    int* csr_src = (int*)alloc((size_t)E * 4);
    int* g_start = (int*)alloc((size_t)(G + 1) * 4);
    float* gsum = (float*)alloc((size_t)G * 64 * 4);
    __hip_bfloat16* h1 = (__hip_bfloat16*)alloc((size_t)N * 128 * 2);   // reused as h2
    __hip_bfloat16* x2n = (__hip_bfloat16*)alloc((size_t)N * 128 * 2);  // bf16, pre-normed
    float* y = (float*)alloc((size_t)N * 64 * 4);
    __hip_bfloat16* h2 = h1;  // h1 dead after spmm1

    hipMemsetAsync(gsum, 0, (size_t)G * 64 * 4, stream);

    const int B = 256;
    // --- atomic-free graph build ---
    passA_count<<<NB, 256, 0, stream>>>(src, dst, E, P, counts, counts + (size_t)NB * P);
    scanB<<<2 * P, 1024, 0, stream>>>(counts, offs, ptot, P);
    scanP<<<1, 512, 0, stream>>>(ptot, pbase, P);
    passC_scatter<<<NB, 256, 0, stream>>>(src, dst, E, P, offs, pbase, ebuf_src, ebuf_dst);
    passD_build<<<P, 512, 0, stream>>>(ebuf_src, ebuf_dst, ptot, pbase, norm_src, row_start,
                                       csr_src, N, E, P);
    gstart_kernel<<<1, 256, 0, stream>>>(gids, g_start, N, G);

    // Layer 1: h1 = (features * norm_src) @ W1   (bf16 MFMA)
    gemm_mfma<128, false><<<768, 256, 0, stream>>>(features, W1, norm_src, h1, N);
    spmm1_kernel<<<(N * 64 + B - 1) / B, B, 0, stream>>>(h1, row_start, csr_src, b1, norm_src,
                                                         (uint*)x2n, N);
    // Layer 2: h2 = x2n @ W2   (x2n already includes norm_src)
    gemm_mfma<64, true><<<768, 256, 0, stream>>>(x2n, W2, nullptr, h2, N);
    spmm2_kernel<<<(N * 64 + B - 1) / B, B, 0, stream>>>(h2, row_start, csr_src, b2, y, N);
    // Per-graph mean
    pool_kernel<<<G * POOL_CHUNKS, 256, 0, stream>>>(y, g_start, gsum);
    finalize_kernel<<<(out_size + B - 1) / B, B, 0, stream>>>(gsum, g_start, out, out_size);
}

// Round 9
// 333.302 us; speedup vs baseline: 1.3777x; 1.2188x over previous
//
#include <hip/hip_runtime.h>
#include <hip/hip_bf16.h>

// ---------------------------------------------------------------------------
// GCN 2-layer forward on MI355X.
// Round 9: SpMM gather MLP. R8 analysis: spmm1 = 1 wave-gather/38 cyc/CU,
// only ~2 loads in flight per wave (latency-bound; HBM 26%). Batch-issue
// 8 independent row gathers per step (then 4/2/1 tails) in both spmm
// kernels. Everything else unchanged from R8.
// ---------------------------------------------------------------------------

#define NPP_SHIFT 9
#define NPP 512
#define MAXP 256
#define NB 512

typedef __attribute__((ext_vector_type(8))) short frag8;
typedef __attribute__((ext_vector_type(4))) float f32x4;

// ---- Pass A: per-block histograms of src-partition and dst-partition ----
__launch_bounds__(256)
__global__ void passA_count(const int* __restrict__ src, const int* __restrict__ dst,
                            int E, int P, int* __restrict__ counts_src,
                            int* __restrict__ counts_dst) {
    __shared__ int h1[MAXP], h2[MAXP];
    int tid = threadIdx.x;
    for (int i = tid; i < P; i += 256) { h1[i] = 0; h2[i] = 0; }
    __syncthreads();
    int per_block = (E + NB - 1) / NB;
    int e0 = blockIdx.x * per_block;
    int e1 = min(e0 + per_block, E);
    for (int e = e0 + tid; e < e1; e += 256) {
        atomicAdd(&h1[src[e] >> NPP_SHIFT], 1);
        atomicAdd(&h2[dst[e] >> NPP_SHIFT], 1);
    }
    __syncthreads();
    for (int i = tid; i < P; i += 256) {
        counts_src[(size_t)blockIdx.x * P + i] = h1[i];
        counts_dst[(size_t)blockIdx.x * P + i] = h2[i];
    }
}

__launch_bounds__(1024)
__global__ void scanB(const int* __restrict__ counts, int* __restrict__ offs,
                      int* __restrict__ ptot, int P) {
    __shared__ int s[1024];
    int tid = threadIdx.x;
    int p = blockIdx.x % P;
    int st = blockIdx.x / P;
    const int* c = counts + (size_t)st * NB * P;
    int v = (tid < NB) ? c[(size_t)tid * P + p] : 0;
    s[tid] = v;
    __syncthreads();
    for (int off = 1; off < 1024; off <<= 1) {
        int t = (tid >= off) ? s[tid - off] : 0;
        __syncthreads();
        s[tid] += t;
        __syncthreads();
    }
    if (tid < NB) offs[(size_t)st * NB * P + (size_t)tid * P + p] = s[tid] - v;
    if (tid == 1023) ptot[st * P + p] = s[1023];
}

__launch_bounds__(512)
__global__ void scanP(const int* __restrict__ ptot, int* __restrict__ pbase, int P) {
    __shared__ int s[512];
    int tid = threadIdx.x;
    int seg = tid >> 8;
    int idx = tid & 255;
    int v = (idx < P) ? ptot[seg * P + idx] : 0;
    s[tid] = v;
    __syncthreads();
    for (int off = 1; off < 256; off <<= 1) {
        int t = (idx >= off) ? s[tid - off] : 0;
        __syncthreads();
        s[tid] += t;
        __syncthreads();
    }
    if (idx < P) pbase[seg * P + idx] = s[tid] - v;
}

__launch_bounds__(256)
__global__ void passC_scatter(const int* __restrict__ src, const int* __restrict__ dst,
                              int E, int P, const int* __restrict__ offs,
                              const int* __restrict__ pbase,
                              int* __restrict__ ebuf_src, int2* __restrict__ ebuf_dst) {
    __shared__ int cur1[MAXP], cur2[MAXP];
    int tid = threadIdx.x;
    for (int i = tid; i < P; i += 256) {
        cur1[i] = pbase[i] + offs[(size_t)blockIdx.x * P + i];
        cur2[i] = pbase[P + i] + offs[(size_t)NB * P + (size_t)blockIdx.x * P + i];
    }
    __syncthreads();
    int per_block = (E + NB - 1) / NB;
    int e0 = blockIdx.x * per_block;
    int e1 = min(e0 + per_block, E);
    for (int e = e0 + tid; e < e1; e += 256) {
        int s = src[e];
        int d = dst[e];
        int pos1 = atomicAdd(&cur1[s >> NPP_SHIFT], 1);
        ebuf_src[pos1] = s;
        int pos2 = atomicAdd(&cur2[d >> NPP_SHIFT], 1);
        ebuf_dst[pos2] = make_int2(d, s);
    }
}

__launch_bounds__(512)
__global__ void passD_build(const int* __restrict__ ebuf_src, const int2* __restrict__ ebuf_dst,
                            const int* __restrict__ ptot, const int* __restrict__ pbase,
                            float* __restrict__ norm_src, int* __restrict__ row_start,
                            int* __restrict__ csr_src, int N, int E, int P) {
    __shared__ int hs[NPP], hd[NPP], sc[NPP];
    int tid = threadIdx.x;
    int p = blockIdx.x;
    int node_lo = p << NPP_SHIFT;
    int nl = min(NPP, N - node_lo);
    hs[tid] = 0;
    hd[tid] = 0;
    __syncthreads();
    int nsrc = ptot[p];
    int base_s = pbase[p];
    for (int i = tid; i < nsrc; i += 512)
        atomicAdd(&hs[ebuf_src[base_s + i] - node_lo], 1);
    int ndst = ptot[P + p];
    int base_d = pbase[P + p];
    for (int i = tid; i < ndst; i += 512)
        atomicAdd(&hd[ebuf_dst[base_d + i].x - node_lo], 1);
    __syncthreads();
    if (tid < nl) norm_src[node_lo + tid] = rsqrtf((float)max(hs[tid], 1));
    int myh = hd[tid];
    sc[tid] = myh;
    __syncthreads();
    for (int off = 1; off < 512; off <<= 1) {
        int t = (tid >= off) ? sc[tid - off] : 0;
        __syncthreads();
        sc[tid] += t;
        __syncthreads();
    }
    int row0 = base_d + sc[tid] - myh;
    if (tid < nl) row_start[node_lo + tid] = row0;
    if (p == P - 1 && tid == 0) row_start[N] = E;
    __syncthreads();
    hd[tid] = row0;  // reuse as cursor
    __syncthreads();
    for (int i = tid; i < ndst; i += 512) {
        int2 r = ebuf_dst[base_d + i];
        int pos = atomicAdd(&hd[r.x - node_lo], 1);
        csr_src[pos] = r.y;
    }
}

__global__ void gstart_kernel(const int* __restrict__ gids, int* __restrict__ g_start,
                              int n, int G) {
    int g = threadIdx.x;
    if (g > G) return;
    int lo = 0, hi = n;
    while (lo < hi) {
        int mid = (lo + hi) >> 1;
        if (gids[mid] < g) lo = mid + 1; else hi = mid;
    }
    g_start[g] = lo;
}

// ---- MFMA GEMM: out[n x COLS](bf16) = A[n x 128] @ W[128 x COLS] --------
template <int COLS, bool BF16IN>
__launch_bounds__(256)
__global__ void gemm_mfma(const void* __restrict__ xin, const float* __restrict__ w,
                          const float* __restrict__ norm,
                          __hip_bfloat16* __restrict__ out, int n) {
    constexpr int NT = COLS / 16;
    __shared__ short wlds[4 * NT * 64 * 8];
    const int tid = threadIdx.x;
    for (int i = tid; i < 128 * COLS / 4; i += 256) {
        int k = (i * 4) / COLS;
        int n0 = (i * 4) % COLS;
        float4 wv = reinterpret_cast<const float4*>(w)[i];
        int c = k >> 5, q = (k >> 3) & 3, j = k & 7;
        float vals[4] = {wv.x, wv.y, wv.z, wv.w};
#pragma unroll
        for (int u = 0; u < 4; ++u) {
            int nn = n0 + u;
            int t = nn >> 4;
            int ln = (q << 4) | (nn & 15);
            union { __hip_bfloat16 b; short s; } cv;
            cv.b = __float2bfloat16(vals[u]);
            wlds[(((c * NT + t) << 6) | ln) * 8 + j] = cv.s;
        }
    }
    __syncthreads();

    const int lane = tid & 63;
    const int wid = tid >> 6;
    const int m = lane & 15;
    const int q = lane >> 4;
    const int ntiles = (n + 15) >> 4;
    const frag8* wfr = reinterpret_cast<const frag8*>(wlds);

    for (int wt = blockIdx.x * 4 + wid; wt < ntiles; wt += gridDim.x * 4) {
        const int row = (wt << 4) + m;
        frag8 af[4];
        if (row < n) {
            if constexpr (BF16IN) {
                const frag8* xp = reinterpret_cast<const frag8*>(
                    (const __hip_bfloat16*)xin + (size_t)row * 128);
#pragma unroll
                for (int c = 0; c < 4; ++c) af[c] = xp[c * 4 + q];
            } else {
                const float* xp = (const float*)xin + (size_t)row * 128;
                float nm = norm[row];
#pragma unroll
                for (int c = 0; c < 4; ++c) {
                    int base = c * 32 + q * 8;
                    float4 v0 = *reinterpret_cast<const float4*>(xp + base);
                    float4 v1 = *reinterpret_cast<const float4*>(xp + base + 4);
                    union { frag8 f; short s[8]; } a;
                    union { __hip_bfloat16 b; short s; } cv;
                    cv.b = __float2bfloat16(v0.x * nm); a.s[0] = cv.s;
                    cv.b = __float2bfloat16(v0.y * nm); a.s[1] = cv.s;
                    cv.b = __float2bfloat16(v0.z * nm); a.s[2] = cv.s;
                    cv.b = __float2bfloat16(v0.w * nm); a.s[3] = cv.s;
                    cv.b = __float2bfloat16(v1.x * nm); a.s[4] = cv.s;
                    cv.b = __float2bfloat16(v1.y * nm); a.s[5] = cv.s;
                    cv.b = __float2bfloat16(v1.z * nm); a.s[6] = cv.s;
                    cv.b = __float2bfloat16(v1.w * nm); a.s[7] = cv.s;
                    af[c] = a.f;
                }
            }
        } else {
#pragma unroll
            for (int c = 0; c < 4; ++c) af[c] = frag8{0, 0, 0, 0, 0, 0, 0, 0};
        }
        f32x4 acc[NT] = {};
#pragma unroll
        for (int c = 0; c < 4; ++c)
#pragma unroll
            for (int t = 0; t < NT; ++t)
                acc[t] = __builtin_amdgcn_mfma_f32_16x16x32_bf16(
                    af[c], wfr[(c * NT + t) * 64 + lane], acc[t], 0, 0, 0);
#pragma unroll
        for (int r = 0; r < 4; ++r) {
            int grow = (wt << 4) + q * 4 + r;
            if (grow < n) {
#pragma unroll
                for (int t = 0; t < NT; ++t)
                    out[(size_t)grow * COLS + t * 16 + m] = __float2bfloat16(acc[t][r]);
            }
        }
    }
}

// ---- SpMM layer 1: wave/dst node, batched gathers (8/4/2/1) -------------
__launch_bounds__(256)
__global__ void spmm1_kernel(const __hip_bfloat16* __restrict__ h,
                             const int* __restrict__ row_start,
                             const int* __restrict__ csr_src,
                             const float* __restrict__ b1,
                             const float* __restrict__ norm_src,
                             uint* __restrict__ out, int n) {
    int gw = (blockIdx.x * blockDim.x + threadIdx.x) >> 6;
    int lane = threadIdx.x & 63;
    if (gw >= n) return;
    int e0 = row_start[gw];
    int e1 = row_start[gw + 1];
    const uint* hp = reinterpret_cast<const uint*>(h);
    float2 acc = {0.f, 0.f};
    int e = e0;
    for (; e + 8 <= e1; e += 8) {
        uint v[8];
#pragma unroll
        for (int j = 0; j < 8; ++j)
            v[j] = hp[(size_t)csr_src[e + j] * 64 + lane];
#pragma unroll
        for (int j = 0; j < 8; ++j) {
            acc.x += __uint_as_float(v[j] << 16);
            acc.y += __uint_as_float(v[j] & 0xffff0000u);
        }
    }
    if (e + 4 <= e1) {
        uint v[4];
#pragma unroll
        for (int j = 0; j < 4; ++j)
            v[j] = hp[(size_t)csr_src[e + j] * 64 + lane];
#pragma unroll
        for (int j = 0; j < 4; ++j) {
            acc.x += __uint_as_float(v[j] << 16);
            acc.y += __uint_as_float(v[j] & 0xffff0000u);
        }
        e += 4;
    }
    if (e + 2 <= e1) {
        uint v0 = hp[(size_t)csr_src[e] * 64 + lane];
        uint v1 = hp[(size_t)csr_src[e + 1] * 64 + lane];
        acc.x += __uint_as_float(v0 << 16);
        acc.y += __uint_as_float(v0 & 0xffff0000u);
        acc.x += __uint_as_float(v1 << 16);
        acc.y += __uint_as_float(v1 & 0xffff0000u);
        e += 2;
    }
    if (e < e1) {
        uint v0 = hp[(size_t)csr_src[e] * 64 + lane];
        acc.x += __uint_as_float(v0 << 16);
        acc.y += __uint_as_float(v0 & 0xffff0000u);
    }
    float nd = rsqrtf((float)max(e1 - e0, 1));
    float ns = norm_src[gw];
    float2 bb = reinterpret_cast<const float2*>(b1)[lane];
    float ox = fmaxf(fmaf(acc.x, nd, bb.x), 0.f) * ns;
    float oy = fmaxf(fmaf(acc.y, nd, bb.y), 0.f) * ns;
    union { __hip_bfloat16 b; ushort s; } cx, cy;
    cx.b = __float2bfloat16(ox);
    cy.b = __float2bfloat16(oy);
    out[(size_t)gw * 64 + lane] = (uint)cx.s | ((uint)cy.s << 16);
}

// ---- SpMM layer 2: wave/dst node, batched gathers (8/4/2/1) -------------
__launch_bounds__(256)
__global__ void spmm2_kernel(const __hip_bfloat16* __restrict__ h,
                             const int* __restrict__ row_start,
                             const int* __restrict__ csr_src,
                             const float* __restrict__ b2, float* __restrict__ y, int n) {
    int gw = (blockIdx.x * blockDim.x + threadIdx.x) >> 6;
    int lane = threadIdx.x & 63;
    if (gw >= n) return;
    int e0 = row_start[gw];
    int e1 = row_start[gw + 1];
    const ushort* hp = reinterpret_cast<const ushort*>(h);
    float acc = 0.f;
    int e = e0;
    for (; e + 8 <= e1; e += 8) {
        uint v[8];
#pragma unroll
        for (int j = 0; j < 8; ++j)
            v[j] = hp[(size_t)csr_src[e + j] * 64 + lane];
#pragma unroll
        for (int j = 0; j < 8; ++j) acc += __uint_as_float(v[j] << 16);
    }
    if (e + 4 <= e1) {
        uint v[4];
#pragma unroll
        for (int j = 0; j < 4; ++j)
            v[j] = hp[(size_t)csr_src[e + j] * 64 + lane];
#pragma unroll
        for (int j = 0; j < 4; ++j) acc += __uint_as_float(v[j] << 16);
        e += 4;
    }
    if (e + 2 <= e1) {
        uint v0 = hp[(size_t)csr_src[e] * 64 + lane];
        uint v1 = hp[(size_t)csr_src[e + 1] * 64 + lane];
        acc += __uint_as_float(v0 << 16);
        acc += __uint_as_float(v1 << 16);
        e += 2;
    }
    if (e < e1) {
        uint v0 = hp[(size_t)csr_src[e] * 64 + lane];
        acc += __uint_as_float(v0 << 16);
    }
    float nd = rsqrtf((float)max(e1 - e0, 1));
    y[(size_t)gw * 64 + lane] = fmaxf(fmaf(acc, nd, b2[lane]), 0.f);
}

// ---- Segmented per-graph pooling over sorted node ranges ----------------
#define POOL_CHUNKS 8
__launch_bounds__(256)
__global__ void pool_kernel(const float* __restrict__ y, const int* __restrict__ g_start,
                            float* __restrict__ gsum) {
    int g = blockIdx.x / POOL_CHUNKS;
    int c = blockIdx.x % POOL_CHUNKS;
    int s = g_start[g];
    int e = g_start[g + 1];
    int lane = threadIdx.x & 63;
    int wave = threadIdx.x >> 6;
    float acc = 0.f;
    for (int i = s + c * 4 + wave; i < e; i += POOL_CHUNKS * 4) {
        acc += y[(size_t)i * 64 + lane];
    }
    __shared__ float sbuf[4][64];
    sbuf[wave][lane] = acc;
    __syncthreads();
    if (wave == 0) {
        float v = sbuf[0][lane] + sbuf[1][lane] + sbuf[2][lane] + sbuf[3][lane];
        atomicAdd(&gsum[(size_t)g * 64 + lane], v);
    }
}

__global__ void finalize_kernel(const float* __restrict__ gsum, const int* __restrict__ g_start,
                                float* __restrict__ out, int total) {
    int i = blockIdx.x * blockDim.x + threadIdx.x;
    if (i < total) {
        int g = i >> 6;
        float cnt = (float)(g_start[g + 1] - g_start[g]);
        out[i] = gsum[i] / fmaxf(cnt, 1.f);
    }
}

extern "C" void kernel_launch(void* const* d_in, const int* in_sizes, int n_in,
                              void* d_out, int out_size, void* d_ws, size_t ws_size,
                              hipStream_t stream) {
    const float* features = (const float*)d_in[0];
    const float* W1 = (const float*)d_in[1];
    const float* b1 = (const float*)d_in[2];
    const float* W2 = (const float*)d_in[3];
    const float* b2 = (const float*)d_in[4];
    const int* src = (const int*)d_in[5];
    const int* dst = (const int*)d_in[6];
    const int* gids = (const int*)d_in[7];
    const int N = in_sizes[7];
    const int E = in_sizes[5];
    const int G = out_size / 64;
    float* out = (float*)d_out;
    const int P = (N + NPP - 1) >> NPP_SHIFT;

    char* ws = (char*)d_ws;
    size_t off = 0;
    auto alloc = [&](size_t bytes) -> void* {
        void* p = ws + off;
        off = (off + bytes + 255) & ~(size_t)255;
        return p;
    };
    int* counts = (int*)alloc((size_t)2 * NB * P * 4);
    int* offs = (int*)alloc((size_t)2 * NB * P * 4);
    int* ptot = (int*)alloc((size_t)2 * P * 4);
    int* pbase = (int*)alloc((size_t)2 * P * 4);
    int* ebuf_src = (int*)alloc((size_t)E * 4);
    int2* ebuf_dst = (int2*)alloc((size_t)E * 8);
    float* norm_src = (float*)alloc((size_t)N * 4);
    int* row_start = (int*)alloc((size_t)(N + 1) * 4);
    int* csr_src = (int*)alloc((size_t)E * 4);
    int* g_start = (int*)alloc((size_t)(G + 1) * 4);
    float* gsum = (float*)alloc((size_t)G * 64 * 4);
    __hip_bfloat16* h1 = (__hip_bfloat16*)alloc((size_t)N * 128 * 2);   // reused as h2
    __hip_bfloat16* x2n = (__hip_bfloat16*)alloc((size_t)N * 128 * 2);  // bf16, pre-normed
    float* y = (float*)alloc((size_t)N * 64 * 4);
    __hip_bfloat16* h2 = h1;  // h1 dead after spmm1

    hipMemsetAsync(gsum, 0, (size_t)G * 64 * 4, stream);

    const int B = 256;
    // --- atomic-free graph build ---
    passA_count<<<NB, 256, 0, stream>>>(src, dst, E, P, counts, counts + (size_t)NB * P);
    scanB<<<2 * P, 1024, 0, stream>>>(counts, offs, ptot, P);
    scanP<<<1, 512, 0, stream>>>(ptot, pbase, P);
    passC_scatter<<<NB, 256, 0, stream>>>(src, dst, E, P, offs, pbase, ebuf_src, ebuf_dst);
    passD_build<<<P, 512, 0, stream>>>(ebuf_src, ebuf_dst, ptot, pbase, norm_src, row_start,
                                       csr_src, N, E, P);
    gstart_kernel<<<1, 256, 0, stream>>>(gids, g_start, N, G);

    // Layer 1: h1 = (features * norm_src) @ W1   (bf16 MFMA)
    gemm_mfma<128, false><<<768, 256, 0, stream>>>(features, W1, norm_src, h1, N);
    spmm1_kernel<<<(N * 64 + B - 1) / B, B, 0, stream>>>(h1, row_start, csr_src, b1, norm_src,
                                                         (uint*)x2n, N);
    // Layer 2: h2 = x2n @ W2   (x2n already includes norm_src)
    gemm_mfma<64, true><<<768, 256, 0, stream>>>(x2n, W2, nullptr, h2, N);
    spmm2_kernel<<<(N * 64 + B - 1) / B, B, 0, stream>>>(h2, row_start, csr_src, b2, y, N);
    // Per-graph mean
    pool_kernel<<<G * POOL_CHUNKS, 256, 0, stream>>>(y, g_start, gsum);
    finalize_kernel<<<(out_size + B - 1) / B, B, 0, stream>>>(gsum, g_start, out, out_size);
}

// Round 10
// 331.810 us; speedup vs baseline: 1.3839x; 1.0045x over previous
//
#include <hip/hip_runtime.h>
#include <hip/hip_bf16.h>

// ---------------------------------------------------------------------------
// GCN 2-layer forward on MI355X.
// Round 10: (1) 16-deep gather batching in both SpMMs (R9: MLP is the spmm
// lever; 8-batch took 100->62 us); (2) dispatch fusion: scanP folded into
// passC (block 0 publishes pbase), pool rewritten as one-block-per-graph
// with inline binary search + divide (kills memset/gstart/finalize);
// (3) y stored as bf16. 15 -> 9 dispatches.
// ---------------------------------------------------------------------------

#define NPP_SHIFT 9
#define NPP 512
#define MAXP 256
#define NB 512

typedef __attribute__((ext_vector_type(8))) short frag8;
typedef __attribute__((ext_vector_type(4))) float f32x4;

// ---- Pass A: per-block histograms of src-partition and dst-partition ----
__launch_bounds__(256)
__global__ void passA_count(const int* __restrict__ src, const int* __restrict__ dst,
                            int E, int P, int* __restrict__ counts_src,
                            int* __restrict__ counts_dst) {
    __shared__ int h1[MAXP], h2[MAXP];
    int tid = threadIdx.x;
    for (int i = tid; i < P; i += 256) { h1[i] = 0; h2[i] = 0; }
    __syncthreads();
    int per_block = (E + NB - 1) / NB;
    int e0 = blockIdx.x * per_block;
    int e1 = min(e0 + per_block, E);
    for (int e = e0 + tid; e < e1; e += 256) {
        atomicAdd(&h1[src[e] >> NPP_SHIFT], 1);
        atomicAdd(&h2[dst[e] >> NPP_SHIFT], 1);
    }
    __syncthreads();
    for (int i = tid; i < P; i += 256) {
        counts_src[(size_t)blockIdx.x * P + i] = h1[i];
        counts_dst[(size_t)blockIdx.x * P + i] = h2[i];
    }
}

// ---- Pass B: exclusive scan across blocks for each (stream, partition) --
__launch_bounds__(1024)
__global__ void scanB(const int* __restrict__ counts, int* __restrict__ offs,
                      int* __restrict__ ptot, int P) {
    __shared__ int s[1024];
    int tid = threadIdx.x;
    int p = blockIdx.x % P;
    int st = blockIdx.x / P;
    const int* c = counts + (size_t)st * NB * P;
    int v = (tid < NB) ? c[(size_t)tid * P + p] : 0;
    s[tid] = v;
    __syncthreads();
    for (int off = 1; off < 1024; off <<= 1) {
        int t = (tid >= off) ? s[tid - off] : 0;
        __syncthreads();
        s[tid] += t;
        __syncthreads();
    }
    if (tid < NB) offs[(size_t)st * NB * P + (size_t)tid * P + p] = s[tid] - v;
    if (tid == 1023) ptot[st * P + p] = s[1023];
}

// ---- Pass C: scatter into partition-bucketed buffers (LDS cursors) ------
// pbase (exclusive scan of ptot per stream) computed in-block from ptot;
// block 0 publishes it to global for passD.
__launch_bounds__(256)
__global__ void passC_scatter(const int* __restrict__ src, const int* __restrict__ dst,
                              int E, int P, const int* __restrict__ offs,
                              const int* __restrict__ ptot, int* __restrict__ pbase,
                              int* __restrict__ ebuf_src, int2* __restrict__ ebuf_dst) {
    __shared__ int cur1[MAXP], cur2[MAXP], sc[256];
    int tid = threadIdx.x;
    // stream 0 scan
    int v = (tid < P) ? ptot[tid] : 0;
    sc[tid] = v;
    __syncthreads();
    for (int off = 1; off < 256; off <<= 1) {
        int t = (tid >= off) ? sc[tid - off] : 0;
        __syncthreads();
        sc[tid] += t;
        __syncthreads();
    }
    int base0 = sc[tid] - v;
    if (tid < P) {
        cur1[tid] = base0 + offs[(size_t)blockIdx.x * P + tid];
        if (blockIdx.x == 0) pbase[tid] = base0;
    }
    __syncthreads();
    // stream 1 scan
    v = (tid < P) ? ptot[P + tid] : 0;
    sc[tid] = v;
    __syncthreads();
    for (int off = 1; off < 256; off <<= 1) {
        int t = (tid >= off) ? sc[tid - off] : 0;
        __syncthreads();
        sc[tid] += t;
        __syncthreads();
    }
    int base1 = sc[tid] - v;
    if (tid < P) {
        cur2[tid] = base1 + offs[(size_t)NB * P + (size_t)blockIdx.x * P + tid];
        if (blockIdx.x == 0) pbase[P + tid] = base1;
    }
    __syncthreads();
    int per_block = (E + NB - 1) / NB;
    int e0 = blockIdx.x * per_block;
    int e1 = min(e0 + per_block, E);
    for (int e = e0 + tid; e < e1; e += 256) {
        int s = src[e];
        int d = dst[e];
        int pos1 = atomicAdd(&cur1[s >> NPP_SHIFT], 1);
        ebuf_src[pos1] = s;
        int pos2 = atomicAdd(&cur2[d >> NPP_SHIFT], 1);
        ebuf_dst[pos2] = make_int2(d, s);
    }
}

// ---- Pass D: per-partition degree/norm/row_start/csr build --------------
__launch_bounds__(512)
__global__ void passD_build(const int* __restrict__ ebuf_src, const int2* __restrict__ ebuf_dst,
                            const int* __restrict__ ptot, const int* __restrict__ pbase,
                            float* __restrict__ norm_src, int* __restrict__ row_start,
                            int* __restrict__ csr_src, int N, int E, int P) {
    __shared__ int hs[NPP], hd[NPP], sc[NPP];
    int tid = threadIdx.x;
    int p = blockIdx.x;
    int node_lo = p << NPP_SHIFT;
    int nl = min(NPP, N - node_lo);
    hs[tid] = 0;
    hd[tid] = 0;
    __syncthreads();
    int nsrc = ptot[p];
    int base_s = pbase[p];
    for (int i = tid; i < nsrc; i += 512)
        atomicAdd(&hs[ebuf_src[base_s + i] - node_lo], 1);
    int ndst = ptot[P + p];
    int base_d = pbase[P + p];
    for (int i = tid; i < ndst; i += 512)
        atomicAdd(&hd[ebuf_dst[base_d + i].x - node_lo], 1);
    __syncthreads();
    if (tid < nl) norm_src[node_lo + tid] = rsqrtf((float)max(hs[tid], 1));
    int myh = hd[tid];
    sc[tid] = myh;
    __syncthreads();
    for (int off = 1; off < 512; off <<= 1) {
        int t = (tid >= off) ? sc[tid - off] : 0;
        __syncthreads();
        sc[tid] += t;
        __syncthreads();
    }
    int row0 = base_d + sc[tid] - myh;
    if (tid < nl) row_start[node_lo + tid] = row0;
    if (p == P - 1 && tid == 0) row_start[N] = E;
    __syncthreads();
    hd[tid] = row0;  // reuse as cursor
    __syncthreads();
    for (int i = tid; i < ndst; i += 512) {
        int2 r = ebuf_dst[base_d + i];
        int pos = atomicAdd(&hd[r.x - node_lo], 1);
        csr_src[pos] = r.y;
    }
}

// ---- MFMA GEMM: out[n x COLS](bf16) = A[n x 128] @ W[128 x COLS] --------
template <int COLS, bool BF16IN>
__launch_bounds__(256)
__global__ void gemm_mfma(const void* __restrict__ xin, const float* __restrict__ w,
                          const float* __restrict__ norm,
                          __hip_bfloat16* __restrict__ out, int n) {
    constexpr int NT = COLS / 16;
    __shared__ short wlds[4 * NT * 64 * 8];
    const int tid = threadIdx.x;
    for (int i = tid; i < 128 * COLS / 4; i += 256) {
        int k = (i * 4) / COLS;
        int n0 = (i * 4) % COLS;
        float4 wv = reinterpret_cast<const float4*>(w)[i];
        int c = k >> 5, q = (k >> 3) & 3, j = k & 7;
        float vals[4] = {wv.x, wv.y, wv.z, wv.w};
#pragma unroll
        for (int u = 0; u < 4; ++u) {
            int nn = n0 + u;
            int t = nn >> 4;
            int ln = (q << 4) | (nn & 15);
            union { __hip_bfloat16 b; short s; } cv;
            cv.b = __float2bfloat16(vals[u]);
            wlds[(((c * NT + t) << 6) | ln) * 8 + j] = cv.s;
        }
    }
    __syncthreads();

    const int lane = tid & 63;
    const int wid = tid >> 6;
    const int m = lane & 15;
    const int q = lane >> 4;
    const int ntiles = (n + 15) >> 4;
    const frag8* wfr = reinterpret_cast<const frag8*>(wlds);

    for (int wt = blockIdx.x * 4 + wid; wt < ntiles; wt += gridDim.x * 4) {
        const int row = (wt << 4) + m;
        frag8 af[4];
        if (row < n) {
            if constexpr (BF16IN) {
                const frag8* xp = reinterpret_cast<const frag8*>(
                    (const __hip_bfloat16*)xin + (size_t)row * 128);
#pragma unroll
                for (int c = 0; c < 4; ++c) af[c] = xp[c * 4 + q];
            } else {
                const float* xp = (const float*)xin + (size_t)row * 128;
                float nm = norm[row];
#pragma unroll
                for (int c = 0; c < 4; ++c) {
                    int base = c * 32 + q * 8;
                    float4 v0 = *reinterpret_cast<const float4*>(xp + base);
                    float4 v1 = *reinterpret_cast<const float4*>(xp + base + 4);
                    union { frag8 f; short s[8]; } a;
                    union { __hip_bfloat16 b; short s; } cv;
                    cv.b = __float2bfloat16(v0.x * nm); a.s[0] = cv.s;
                    cv.b = __float2bfloat16(v0.y * nm); a.s[1] = cv.s;
                    cv.b = __float2bfloat16(v0.z * nm); a.s[2] = cv.s;
                    cv.b = __float2bfloat16(v0.w * nm); a.s[3] = cv.s;
                    cv.b = __float2bfloat16(v1.x * nm); a.s[4] = cv.s;
                    cv.b = __float2bfloat16(v1.y * nm); a.s[5] = cv.s;
                    cv.b = __float2bfloat16(v1.z * nm); a.s[6] = cv.s;
                    cv.b = __float2bfloat16(v1.w * nm); a.s[7] = cv.s;
                    af[c] = a.f;
                }
            }
        } else {
#pragma unroll
            for (int c = 0; c < 4; ++c) af[c] = frag8{0, 0, 0, 0, 0, 0, 0, 0};
        }
        f32x4 acc[NT] = {};
#pragma unroll
        for (int c = 0; c < 4; ++c)
#pragma unroll
            for (int t = 0; t < NT; ++t)
                acc[t] = __builtin_amdgcn_mfma_f32_16x16x32_bf16(
                    af[c], wfr[(c * NT + t) * 64 + lane], acc[t], 0, 0, 0);
#pragma unroll
        for (int r = 0; r < 4; ++r) {
            int grow = (wt << 4) + q * 4 + r;
            if (grow < n) {
#pragma unroll
                for (int t = 0; t < NT; ++t)
                    out[(size_t)grow * COLS + t * 16 + m] = __float2bfloat16(acc[t][r]);
            }
        }
    }
}

// ---- SpMM layer 1: wave/dst node, batched gathers (16/8/4/2/1) ----------
__launch_bounds__(256)
__global__ void spmm1_kernel(const __hip_bfloat16* __restrict__ h,
                             const int* __restrict__ row_start,
                             const int* __restrict__ csr_src,
                             const float* __restrict__ b1,
                             const float* __restrict__ norm_src,
                             uint* __restrict__ out, int n) {
    int gw = (blockIdx.x * blockDim.x + threadIdx.x) >> 6;
    int lane = threadIdx.x & 63;
    if (gw >= n) return;
    int e0 = row_start[gw];
    int e1 = row_start[gw + 1];
    const uint* hp = reinterpret_cast<const uint*>(h);
    float2 acc = {0.f, 0.f};
    int e = e0;
    for (; e + 16 <= e1; e += 16) {
        uint v[16];
#pragma unroll
        for (int j = 0; j < 16; ++j)
            v[j] = hp[(size_t)csr_src[e + j] * 64 + lane];
#pragma unroll
        for (int j = 0; j < 16; ++j) {
            acc.x += __uint_as_float(v[j] << 16);
            acc.y += __uint_as_float(v[j] & 0xffff0000u);
        }
    }
    if (e + 8 <= e1) {
        uint v[8];
#pragma unroll
        for (int j = 0; j < 8; ++j)
            v[j] = hp[(size_t)csr_src[e + j] * 64 + lane];
#pragma unroll
        for (int j = 0; j < 8; ++j) {
            acc.x += __uint_as_float(v[j] << 16);
            acc.y += __uint_as_float(v[j] & 0xffff0000u);
        }
        e += 8;
    }
    if (e + 4 <= e1) {
        uint v[4];
#pragma unroll
        for (int j = 0; j < 4; ++j)
            v[j] = hp[(size_t)csr_src[e + j] * 64 + lane];
#pragma unroll
        for (int j = 0; j < 4; ++j) {
            acc.x += __uint_as_float(v[j] << 16);
            acc.y += __uint_as_float(v[j] & 0xffff0000u);
        }
        e += 4;
    }
    if (e + 2 <= e1) {
        uint v0 = hp[(size_t)csr_src[e] * 64 + lane];
        uint v1 = hp[(size_t)csr_src[e + 1] * 64 + lane];
        acc.x += __uint_as_float(v0 << 16);
        acc.y += __uint_as_float(v0 & 0xffff0000u);
        acc.x += __uint_as_float(v1 << 16);
        acc.y += __uint_as_float(v1 & 0xffff0000u);
        e += 2;
    }
    if (e < e1) {
        uint v0 = hp[(size_t)csr_src[e] * 64 + lane];
        acc.x += __uint_as_float(v0 << 16);
        acc.y += __uint_as_float(v0 & 0xffff0000u);
    }
    float nd = rsqrtf((float)max(e1 - e0, 1));
    float ns = norm_src[gw];
    float2 bb = reinterpret_cast<const float2*>(b1)[lane];
    float ox = fmaxf(fmaf(acc.x, nd, bb.x), 0.f) * ns;
    float oy = fmaxf(fmaf(acc.y, nd, bb.y), 0.f) * ns;
    union { __hip_bfloat16 b; ushort s; } cx, cy;
    cx.b = __float2bfloat16(ox);
    cy.b = __float2bfloat16(oy);
    out[(size_t)gw * 64 + lane] = (uint)cx.s | ((uint)cy.s << 16);
}

// ---- SpMM layer 2: wave/dst node, batched gathers; emits bf16 y ---------
__launch_bounds__(256)
__global__ void spmm2_kernel(const __hip_bfloat16* __restrict__ h,
                             const int* __restrict__ row_start,
                             const int* __restrict__ csr_src,
                             const float* __restrict__ b2, ushort* __restrict__ y, int n) {
    int gw = (blockIdx.x * blockDim.x + threadIdx.x) >> 6;
    int lane = threadIdx.x & 63;
    if (gw >= n) return;
    int e0 = row_start[gw];
    int e1 = row_start[gw + 1];
    const ushort* hp = reinterpret_cast<const ushort*>(h);
    float acc = 0.f;
    int e = e0;
    for (; e + 16 <= e1; e += 16) {
        uint v[16];
#pragma unroll
        for (int j = 0; j < 16; ++j)
            v[j] = hp[(size_t)csr_src[e + j] * 64 + lane];
#pragma unroll
        for (int j = 0; j < 16; ++j) acc += __uint_as_float(v[j] << 16);
    }
    if (e + 8 <= e1) {
        uint v[8];
#pragma unroll
        for (int j = 0; j < 8; ++j)
            v[j] = hp[(size_t)csr_src[e + j] * 64 + lane];
#pragma unroll
        for (int j = 0; j < 8; ++j) acc += __uint_as_float(v[j] << 16);
        e += 8;
    }
    if (e + 4 <= e1) {
        uint v[4];
#pragma unroll
        for (int j = 0; j < 4; ++j)
            v[j] = hp[(size_t)csr_src[e + j] * 64 + lane];
#pragma unroll
        for (int j = 0; j < 4; ++j) acc += __uint_as_float(v[j] << 16);
        e += 4;
    }
    if (e + 2 <= e1) {
        uint v0 = hp[(size_t)csr_src[e] * 64 + lane];
        uint v1 = hp[(size_t)csr_src[e + 1] * 64 + lane];
        acc += __uint_as_float(v0 << 16);
        acc += __uint_as_float(v1 << 16);
        e += 2;
    }
    if (e < e1) {
        uint v0 = hp[(size_t)csr_src[e] * 64 + lane];
        acc += __uint_as_float(v0 << 16);
    }
    float nd = rsqrtf((float)max(e1 - e0, 1));
    float val = fmaxf(fmaf(acc, nd, b2[lane]), 0.f);
    union { __hip_bfloat16 b; ushort s; } cv;
    cv.b = __float2bfloat16(val);
    y[(size_t)gw * 64 + lane] = cv.s;
}

// ---- Fused pooling: one block per graph, binary-search bounds, divide ---
__launch_bounds__(256)
__global__ void pool_kernel(const ushort* __restrict__ y, const int* __restrict__ gids,
                            float* __restrict__ out, int n) {
    int g = blockIdx.x;
    int lo = 0, hi = n;
    while (lo < hi) {
        int mid = (lo + hi) >> 1;
        if (gids[mid] < g) lo = mid + 1; else hi = mid;
    }
    int s = lo;
    hi = n;
    while (lo < hi) {
        int mid = (lo + hi) >> 1;
        if (gids[mid] < g + 1) lo = mid + 1; else hi = mid;
    }
    int e = lo;
    int lane = threadIdx.x & 63;
    int wave = threadIdx.x >> 6;
    float acc = 0.f;
    int i = s + wave;
    for (; i + 12 < e; i += 16) {
        uint u0 = y[(size_t)(i + 0) * 64 + lane];
        uint u1 = y[(size_t)(i + 4) * 64 + lane];
        uint u2 = y[(size_t)(i + 8) * 64 + lane];
        uint u3 = y[(size_t)(i + 12) * 64 + lane];
        acc += __uint_as_float(u0 << 16) + __uint_as_float(u1 << 16) +
               __uint_as_float(u2 << 16) + __uint_as_float(u3 << 16);
    }
    for (; i < e; i += 4)
        acc += __uint_as_float((uint)y[(size_t)i * 64 + lane] << 16);
    __shared__ float sbuf[4][64];
    sbuf[wave][lane] = acc;
    __syncthreads();
    if (wave == 0) {
        float v = sbuf[0][lane] + sbuf[1][lane] + sbuf[2][lane] + sbuf[3][lane];
        out[(size_t)g * 64 + lane] = v / fmaxf((float)(e - s), 1.f);
    }
}

extern "C" void kernel_launch(void* const* d_in, const int* in_sizes, int n_in,
                              void* d_out, int out_size, void* d_ws, size_t ws_size,
                              hipStream_t stream) {
    const float* features = (const float*)d_in[0];
    const float* W1 = (const float*)d_in[1];
    const float* b1 = (const float*)d_in[2];
    const float* W2 = (const float*)d_in[3];
    const float* b2 = (const float*)d_in[4];
    const int* src = (const int*)d_in[5];
    const int* dst = (const int*)d_in[6];
    const int* gids = (const int*)d_in[7];
    const int N = in_sizes[7];
    const int E = in_sizes[5];
    const int G = out_size / 64;
    float* out = (float*)d_out;
    const int P = (N + NPP - 1) >> NPP_SHIFT;

    char* ws = (char*)d_ws;
    size_t off = 0;
    auto alloc = [&](size_t bytes) -> void* {
        void* p = ws + off;
        off = (off + bytes + 255) & ~(size_t)255;
        return p;
    };
    int* counts = (int*)alloc((size_t)2 * NB * P * 4);
    int* offs = (int*)alloc((size_t)2 * NB * P * 4);
    int* ptot = (int*)alloc((size_t)2 * P * 4);
    int* pbase = (int*)alloc((size_t)2 * P * 4);
    int* ebuf_src = (int*)alloc((size_t)E * 4);
    int2* ebuf_dst = (int2*)alloc((size_t)E * 8);
    float* norm_src = (float*)alloc((size_t)N * 4);
    int* row_start = (int*)alloc((size_t)(N + 1) * 4);
    int* csr_src = (int*)alloc((size_t)E * 4);
    __hip_bfloat16* h1 = (__hip_bfloat16*)alloc((size_t)N * 128 * 2);   // reused as h2
    __hip_bfloat16* x2n = (__hip_bfloat16*)alloc((size_t)N * 128 * 2);  // bf16, pre-normed
    ushort* y = (ushort*)alloc((size_t)N * 64 * 2);                     // bf16
    __hip_bfloat16* h2 = h1;  // h1 dead after spmm1

    const int B = 256;
    // --- atomic-free graph build (pbase published by passC block 0) ---
    passA_count<<<NB, 256, 0, stream>>>(src, dst, E, P, counts, counts + (size_t)NB * P);
    scanB<<<2 * P, 1024, 0, stream>>>(counts, offs, ptot, P);
    passC_scatter<<<NB, 256, 0, stream>>>(src, dst, E, P, offs, ptot, pbase,
                                          ebuf_src, ebuf_dst);
    passD_build<<<P, 512, 0, stream>>>(ebuf_src, ebuf_dst, ptot, pbase, norm_src, row_start,
                                       csr_src, N, E, P);

    // Layer 1: h1 = (features * norm_src) @ W1   (bf16 MFMA)
    gemm_mfma<128, false><<<768, 256, 0, stream>>>(features, W1, norm_src, h1, N);
    spmm1_kernel<<<(N * 64 + B - 1) / B, B, 0, stream>>>(h1, row_start, csr_src, b1, norm_src,
                                                         (uint*)x2n, N);
    // Layer 2: h2 = x2n @ W2   (x2n already includes norm_src)
    gemm_mfma<64, true><<<768, 256, 0, stream>>>(x2n, W2, nullptr, h2, N);
    spmm2_kernel<<<(N * 64 + B - 1) / B, B, 0, stream>>>(h2, row_start, csr_src, b2, y, N);
    // Per-graph mean (one block per graph; sorted gids)
    pool_kernel<<<G, 256, 0, stream>>>(y, gids, out, N);
}